// Round 1
// 828.810 us; speedup vs baseline: 1.0654x; 1.0654x over previous
//
#include <hip/hip_runtime.h>
#include <math.h>
#include <stdint.h>

typedef _Float16 f16;
typedef _Float16 f16x8 __attribute__((ext_vector_type(8)));
typedef float f32x4 __attribute__((ext_vector_type(4)));

#define B_    16
#define T_    4096
#define SEM   512
#define ACO   32
#define XROWS 544
#define CODES 2048
#define EPSC  1e-5f
#define HALFC 4.0f
#define ECLAMP 60000.0f

// ---- ws layout (float units) ----
// embT   [0, 1048576)              fp32 [512][2048] for finalize gather
// bias   [1048576, 1050624)        0.5*|e|^2
// codesW [1050624, 1116160)        int[65536]
// EhT    [1116160, 1640448)        f16[2048][512] (high half)
// ElT    [1640448, 2164736)        f16[2048][512] (low half)
// pScore [2164736, 2426880)        float[4][65536]
// pIdx   [2426880, 2689024)        int[4][65536]
//
// X hi/lo planes live in the OUTPUT buffer as scratch (finalize overwrites
// them only after argmin has consumed them):
// XhT = out[0, 16777216)  floats   = f16[65536][512]
// XlT = out[16777216, 33554432)    = f16[65536][512]   (QOFF = 35651584 > end)

// ============ kernel 1: per-code bias = 0.5*|e|^2 ============
__global__ void bias_kernel(const float* __restrict__ esum,
                            const float* __restrict__ usage,
                            float* __restrict__ bias) {
    int c = blockIdx.x;
    float u = fmaxf(usage[c], EPSC);
    float s = 0.f;
    for (int d = threadIdx.x; d < SEM; d += 64) {
        float v = esum[(size_t)c * SEM + d] / u;
        s += v * v;
    }
    for (int off = 32; off; off >>= 1) s += __shfl_down(s, off);
    if (threadIdx.x == 0) bias[c] = 0.5f * s;
}

// ============ kernel 2: embT[d][c] = esum[c][d] / clip(usage[c]) ============
__global__ void embT_kernel(const float* __restrict__ esum,
                            const float* __restrict__ usage,
                            float* __restrict__ embT) {
    __shared__ float tile[32][33];
    int c0 = blockIdx.x * 32;
    int d0 = blockIdx.y * 32;
    int col = threadIdx.x & 31, r = threadIdx.x >> 5;  // 256 threads: r=0..7
    for (int i = r; i < 32; i += 8) {
        float u = fmaxf(usage[c0 + i], EPSC);
        tile[col][i] = esum[(size_t)(c0 + i) * SEM + d0 + col] / u;
    }
    __syncthreads();
    for (int i = r; i < 32; i += 8)
        embT[(size_t)(d0 + i) * CODES + c0 + col] = tile[i][col];
}

// ============ kernel 3: f16 hi/lo split planes of emb, [c][d] layout ============
__global__ void esplit_kernel(const float* __restrict__ esum,
                              const float* __restrict__ usage,
                              f16* __restrict__ EhT, f16* __restrict__ ElT) {
    int c = blockIdx.x;
    float u = fmaxf(usage[c], EPSC);
    for (int d = threadIdx.x; d < SEM; d += 256) {
        float e = esum[(size_t)c * SEM + d] / u;
        e = fminf(fmaxf(e, -ECLAMP), ECLAMP);
        f16 h = (f16)e;
        EhT[(size_t)c * SEM + d] = h;
        ElT[(size_t)c * SEM + d] = (f16)(e - (float)h);
    }
}

// ============ kernel 3b: transpose+split x -> XhT/XlT [m][k] f16 ============
// block: 256 threads = 256 consecutive t for one b; 32 d per block (grid.y)
// reads coalesced along t (256B/row); writes 64B contiguous per lane per plane
__global__ void xsplit_kernel(const float* __restrict__ x,
                              f16* __restrict__ XhT, f16* __restrict__ XlT) {
    int m0 = blockIdx.x * 256;
    int d0 = blockIdx.y * 32;
    int b  = m0 >> 12;
    int t  = (m0 & 4095) + (int)threadIdx.x;
    const float* xp = x + ((size_t)b * XROWS + d0) * T_ + t;
    int m = m0 + (int)threadIdx.x;

    f16x8 hv[4], lv[4];
#pragma unroll
    for (int j = 0; j < 4; j++) {
#pragma unroll
        for (int e = 0; e < 8; e++) {
            float v = xp[(size_t)(j * 8 + e) * T_];
            f16 h = (f16)v;
            hv[j][e] = h;
            lv[j][e] = (f16)(v - (float)h);
        }
    }
    f16* oh = XhT + (size_t)m * SEM + d0;
    f16* ol = XlT + (size_t)m * SEM + d0;
#pragma unroll
    for (int j = 0; j < 4; j++) {
        *(f16x8*)(oh + j * 8) = hv[j];
        *(f16x8*)(ol + j * 8) = lv[j];
    }
}

// ============ kernel 4: MFMA GEMM + fused argmin (all-f16 LDS, gload_lds) ============
#define MB 256
#define NQ 512
#define NC 128
#define BK 32

__device__ __forceinline__ void gl_lds16(const f16* g, f16* l) {
    __builtin_amdgcn_global_load_lds(
        (const __attribute__((address_space(1))) unsigned int*)(g),
        (__attribute__((address_space(3))) unsigned int*)(l),
        16, 0, 0);
}

__global__ __launch_bounds__(256, 2) void argmin_mfma(
        const f16* __restrict__ XhT, const f16* __restrict__ XlT,
        const f16* __restrict__ EhT, const f16* __restrict__ ElT,
        const float* __restrict__ bias,
        float* __restrict__ pScore, int* __restrict__ pIdx) {
    // rows of 32 f16 = 64B -> 16B-column b128 reads are bank-minimal (8 lanes/bank)
    __shared__ __align__(16) f16 Xh[MB * BK];   // [256][32]
    __shared__ __align__(16) f16 Xl[MB * BK];
    __shared__ __align__(16) f16 Eh[NC * BK];   // [128][32]
    __shared__ __align__(16) f16 El[NC * BK];

    int tid = threadIdx.x;
    int w   = tid >> 6;        // wave 0..3
    int l   = tid & 63;
    int q   = l >> 4;          // quad
    int r16 = l & 15;

    int m0      = blockIdx.x * MB;     // query base
    int quarter = blockIdx.y;          // 0..3 code quarter

    // per-lane LDS frag offsets (f16 units)
    int aoff = (w * 64 + r16) * BK + q * 8;   // + mi*16*BK
    int boff = r16 * BK + q * 8;              // + ni*16*BK

    float bestS[16];
    int   bestI[16];
#pragma unroll
    for (int i = 0; i < 16; i++) { bestS[i] = -3.4e38f; bestI[i] = 0; }

    for (int nc = 0; nc < 4; nc++) {
        int nbase = quarter * NQ + nc * NC;
        float bb[8];
#pragma unroll
        for (int ni = 0; ni < 8; ni++) bb[ni] = bias[nbase + ni * 16 + r16];

        f32x4 acc[4][8];
#pragma unroll
        for (int mi = 0; mi < 4; mi++)
#pragma unroll
            for (int ni = 0; ni < 8; ni++)
                acc[mi][ni] = (f32x4){0.f, 0.f, 0.f, 0.f};

        for (int k0 = 0; k0 < SEM; k0 += BK) {
            __syncthreads();   // previous tile fully consumed
            // stage X hi/lo: [256][32] f16 per plane = 1024 x 16B chunks
            // dest chunk off16 = ii*256+tid (lane-linear); m = off16>>2, ch = off16&3
#pragma unroll
            for (int ii = 0; ii < 4; ii++) {
                int off16 = ii * 256 + tid;
                int mm = off16 >> 2, ch = off16 & 3;
                int gsrc = (m0 + mm) * SEM + k0 + ch * 8;    // f16 units, < 2^25
                gl_lds16(XhT + gsrc, Xh + off16 * 8);
                gl_lds16(XlT + gsrc, Xl + off16 * 8);
            }
            // stage E hi/lo: [128][32] f16 per plane = 512 x 16B chunks
#pragma unroll
            for (int ii = 0; ii < 2; ii++) {
                int off16 = ii * 256 + tid;
                int nn = off16 >> 2, ch = off16 & 3;
                int gsrc = (nbase + nn) * SEM + k0 + ch * 8;
                gl_lds16(EhT + gsrc, Eh + off16 * 8);
                gl_lds16(ElT + gsrc, El + off16 * 8);
            }
            __syncthreads();   // vmcnt(0) drain inserted by compiler

            f16x8 ah[4], al[4];
#pragma unroll
            for (int mi = 0; mi < 4; mi++) {
                ah[mi] = *(const f16x8*)&Xh[aoff + mi * 16 * BK];
                al[mi] = *(const f16x8*)&Xl[aoff + mi * 16 * BK];
            }
#pragma unroll
            for (int ni = 0; ni < 8; ni++) {
                f16x8 bh = *(const f16x8*)&Eh[boff + ni * 16 * BK];
                f16x8 bl = *(const f16x8*)&El[boff + ni * 16 * BK];
#pragma unroll
                for (int mi = 0; mi < 4; mi++) {
                    f32x4 a0 = acc[mi][ni];
                    a0 = __builtin_amdgcn_mfma_f32_16x16x32_f16(al[mi], bh, a0, 0, 0, 0);
                    a0 = __builtin_amdgcn_mfma_f32_16x16x32_f16(ah[mi], bl, a0, 0, 0, 0);
                    a0 = __builtin_amdgcn_mfma_f32_16x16x32_f16(ah[mi], bh, a0, 0, 0, 0);
                    acc[mi][ni] = a0;
                }
            }
        }
        // epilogue: fold bias, update per-lane argmax (n ascending -> smallest idx kept)
#pragma unroll
        for (int ni = 0; ni < 8; ni++) {
            int n = nbase + ni * 16 + r16;
#pragma unroll
            for (int mi = 0; mi < 4; mi++)
#pragma unroll
                for (int reg = 0; reg < 4; reg++) {
                    float s = acc[mi][ni][reg] - bb[ni];
                    int slot = mi * 4 + reg;
                    if (s > bestS[slot]) { bestS[slot] = s; bestI[slot] = n; }
                }
        }
    }

    // reduce across the 16 column-lanes (bits 0..3), tie -> smallest idx
#pragma unroll
    for (int mask = 1; mask < 16; mask <<= 1) {
#pragma unroll
        for (int slot = 0; slot < 16; slot++) {
            float os = __shfl_xor(bestS[slot], mask);
            int   oi = __shfl_xor(bestI[slot], mask);
            if (os > bestS[slot] || (os == bestS[slot] && oi < bestI[slot])) {
                bestS[slot] = os; bestI[slot] = oi;
            }
        }
    }
    if (r16 == 0) {
#pragma unroll
        for (int mi = 0; mi < 4; mi++)
#pragma unroll
            for (int reg = 0; reg < 4; reg++) {
                int m = m0 + w * 64 + mi * 16 + q * 4 + reg;
                pScore[quarter * 65536 + m] = bestS[mi * 4 + reg];
                pIdx  [quarter * 65536 + m] = bestI[mi * 4 + reg];
            }
    }
}

// ============ kernel 5: merge the 4 quarter-partials ============
__global__ void merge_kernel(const float* __restrict__ pScore,
                             const int* __restrict__ pIdx,
                             int* __restrict__ codesW,
                             float* __restrict__ codes_out) {
    int m = blockIdx.x * 256 + threadIdx.x;
    float bs = pScore[m]; int bi = pIdx[m];
    for (int qq = 1; qq < 4; qq++) {
        float s = pScore[qq * 65536 + m];
        int  ii = pIdx[qq * 65536 + m];
        if (s > bs || (s == bs && ii < bi)) { bs = s; bi = ii; }
    }
    codesW[m] = bi;
    int bb2 = m >> 12, t = m & 4095;
    codes_out[(size_t)bb2 * 33 * T_ + t] = (float)bi;
}

// ============ kernel 6: finalize (sem select/gather + aco path) ============
__global__ void finalize_kernel(const float* __restrict__ x,
                                const float* __restrict__ embT,
                                const int* __restrict__ codes_ws,
                                const float* __restrict__ noise,
                                const float* __restrict__ probs_sem,
                                const float* __restrict__ probs_aco,
                                float* __restrict__ out,
                                float* __restrict__ codes_out) {
    const size_t N0 = (size_t)B_ * SEM * T_;   // 33,554,432
    const size_t N1 = (size_t)B_ * ACO * T_;   // 2,097,152
    size_t idx = (size_t)blockIdx.x * 256 + threadIdx.x;
    if (idx < N0) {
        int t = (int)(idx & 4095);
        int d = (int)((idx >> 12) & 511);
        int b = (int)(idx >> 21);
        float v;
        if (probs_sem[b] < 0.5f) {
            int c = codes_ws[(b << 12) + t];
            v = embT[(size_t)d * CODES + c];
        } else {
            v = x[((size_t)(b * XROWS + d)) * T_ + t];
        }
        out[((size_t)(b * XROWS + d)) * T_ + t] = v;
    } else if (idx < N0 + N1) {
        size_t i2 = idx - N0;
        int t = (int)(i2 & 4095);
        int j = (int)((i2 >> 12) & 31);
        int b = (int)(i2 >> 17);
        float a  = x[((size_t)(b * XROWS + SEM + j)) * T_ + t];
        float zb = tanhf(a) * HALFC;
        float p  = probs_aco[b];
        float zo;
        if (p < 0.5f) {
            zo = rintf(zb);                         // round-half-even, matches jnp.round
        } else if (p < 0.75f) {
            float nz = noise[((size_t)(b * ACO + j)) * T_ + t];
            float ns = ((nz * 2.0f - 1.0f) * (float)(1.0 / 9.0)) * HALFC;
            zo = fminf(fmaxf(zb + ns, -HALFC), HALFC);
        } else {
            zo = zb;
        }
        float code = fminf(fmaxf(rintf(zo + HALFC), 0.f), 8.f);
        out[((size_t)(b * XROWS + SEM + j)) * T_ + t] = zo * 0.25f;
        codes_out[((size_t)(b * 33 + 1 + j)) * T_ + t] = code;
    }
}

extern "C" void kernel_launch(void* const* d_in, const int* in_sizes, int n_in,
                              void* d_out, int out_size, void* d_ws, size_t ws_size,
                              hipStream_t stream) {
    const float* x      = (const float*)d_in[0];
    const float* esum   = (const float*)d_in[1];
    const float* usage  = (const float*)d_in[2];
    const float* noise  = (const float*)d_in[3];
    const float* psem   = (const float*)d_in[4];
    const float* paco   = (const float*)d_in[5];
    float* out = (float*)d_out;

    float* wsf    = (float*)d_ws;
    float* embT   = wsf;
    float* bias   = wsf + 1048576;
    int*   codesW = (int*)(wsf + 1050624);
    f16*   EhT    = (f16*)(wsf + 1116160);
    f16*   ElT    = (f16*)(wsf + 1640448);
    float* pScore = wsf + 2164736;
    int*   pIdx   = (int*)(wsf + 2426880);

    const size_t QOFF = (size_t)B_ * XROWS * T_;   // 35,651,584
    float* codes_out = out + QOFF;

    // X hi/lo scratch inside the output buffer (consumed before finalize writes)
    f16* XhT = (f16*)out;                    // 64 MB
    f16* XlT = (f16*)(out + 16777216);       // 64 MB, ends at 33,554,432 < QOFF

    xsplit_kernel<<<dim3((B_ * T_) / 256, SEM / 32), 256, 0, stream>>>(x, XhT, XlT);
    bias_kernel<<<CODES, 64, 0, stream>>>(esum, usage, bias);
    embT_kernel<<<dim3(CODES / 32, SEM / 32), 256, 0, stream>>>(esum, usage, embT);
    esplit_kernel<<<CODES, 256, 0, stream>>>(esum, usage, EhT, ElT);
    argmin_mfma<<<dim3((B_ * T_) / MB, 4), 256, 0, stream>>>(XhT, XlT, EhT, ElT,
                                                             bias, pScore, pIdx);
    merge_kernel<<<(B_ * T_) / 256, 256, 0, stream>>>(pScore, pIdx, codesW, codes_out);
    const size_t NTOT = (size_t)B_ * SEM * T_ + (size_t)B_ * ACO * T_;
    finalize_kernel<<<(int)(NTOT / 256), 256, 0, stream>>>(x, embT, codesW, noise,
                                                           psem, paco, out, codes_out);
}

// Round 3
// 719.304 us; speedup vs baseline: 1.2276x; 1.1522x over previous
//
#include <hip/hip_runtime.h>
#include <math.h>
#include <stdint.h>

typedef _Float16 f16;
typedef _Float16 f16x8 __attribute__((ext_vector_type(8)));
typedef float f32x4 __attribute__((ext_vector_type(4)));

#define B_    16
#define T_    4096
#define SEM   512
#define ACO   32
#define XROWS 544
#define CODES 2048
#define EPSC  1e-5f
#define HALFC 4.0f
#define ECLAMP 60000.0f

// ---- ws layout (float units) ----
// embT   [0, 1048576)              fp32 [512][2048] for finalize gather
// bias   [1048576, 1050624)        0.5*|e|^2
// codesW [1050624, 1116160)        int[65536]
// EhT    [1116160, 1640448)        f16[2048][512] (high half)
// ElT    [1640448, 2164736)        f16[2048][512] (low half)
//
// X hi/lo planes live in the OUTPUT buffer as scratch (finalize overwrites
// them only after argmin has consumed them):
// XhT = out[0, 16777216)  floats   = f16[65536][512]
// XlT = out[16777216, 33554432)    = f16[65536][512]   (QOFF = 35651584 > end)

// ============ kernel 1: per-code bias = 0.5*|e|^2 ============
__global__ void bias_kernel(const float* __restrict__ esum,
                            const float* __restrict__ usage,
                            float* __restrict__ bias) {
    int c = blockIdx.x;
    float u = fmaxf(usage[c], EPSC);
    float s = 0.f;
    for (int d = threadIdx.x; d < SEM; d += 64) {
        float v = esum[(size_t)c * SEM + d] / u;
        s += v * v;
    }
    for (int off = 32; off; off >>= 1) s += __shfl_down(s, off);
    if (threadIdx.x == 0) bias[c] = 0.5f * s;
}

// ============ kernel 2: embT[d][c] = esum[c][d] / clip(usage[c]) ============
__global__ void embT_kernel(const float* __restrict__ esum,
                            const float* __restrict__ usage,
                            float* __restrict__ embT) {
    __shared__ float tile[32][33];
    int c0 = blockIdx.x * 32;
    int d0 = blockIdx.y * 32;
    int col = threadIdx.x & 31, r = threadIdx.x >> 5;  // 256 threads: r=0..7
    for (int i = r; i < 32; i += 8) {
        float u = fmaxf(usage[c0 + i], EPSC);
        tile[col][i] = esum[(size_t)(c0 + i) * SEM + d0 + col] / u;
    }
    __syncthreads();
    for (int i = r; i < 32; i += 8)
        embT[(size_t)(d0 + i) * CODES + c0 + col] = tile[i][col];
}

// ============ kernel 3: f16 hi/lo split planes of emb, [c][d] layout ============
__global__ void esplit_kernel(const float* __restrict__ esum,
                              const float* __restrict__ usage,
                              f16* __restrict__ EhT, f16* __restrict__ ElT) {
    int c = blockIdx.x;
    float u = fmaxf(usage[c], EPSC);
    for (int d = threadIdx.x; d < SEM; d += 256) {
        float e = esum[(size_t)c * SEM + d] / u;
        e = fminf(fmaxf(e, -ECLAMP), ECLAMP);
        f16 h = (f16)e;
        EhT[(size_t)c * SEM + d] = h;
        ElT[(size_t)c * SEM + d] = (f16)(e - (float)h);
    }
}

// ============ kernel 3b: transpose+split x -> XhT/XlT [m][k] f16 ============
__global__ void xsplit_kernel(const float* __restrict__ x,
                              f16* __restrict__ XhT, f16* __restrict__ XlT) {
    int m0 = blockIdx.x * 256;
    int d0 = blockIdx.y * 32;
    int b  = m0 >> 12;
    int t  = (m0 & 4095) + (int)threadIdx.x;
    const float* xp = x + ((size_t)b * XROWS + d0) * T_ + t;
    int m = m0 + (int)threadIdx.x;

    f16x8 hv[4], lv[4];
#pragma unroll
    for (int j = 0; j < 4; j++) {
#pragma unroll
        for (int e = 0; e < 8; e++) {
            float v = xp[(size_t)(j * 8 + e) * T_];
            f16 h = (f16)v;
            hv[j][e] = h;
            lv[j][e] = (f16)(v - (float)h);
        }
    }
    f16* oh = XhT + (size_t)m * SEM + d0;
    f16* ol = XlT + (size_t)m * SEM + d0;
#pragma unroll
    for (int j = 0; j < 4; j++) {
        *(f16x8*)(oh + j * 8) = hv[j];
        *(f16x8*)(ol + j * 8) = lv[j];
    }
}

// ============ kernel 4: MFMA GEMM + fused argmin ============
// 512 threads (8 waves = 4M x 2N), MB=256 m-rows, full N=2048 per block via
// 8 nc-chunks of 256 codes; double-buffered LDS (2 x 64 KB) with
// prefetch-before-compute: one barrier per k-tile.
// Wave pair (wm, wn=0/1) splits each 256-code chunk; merged via LDS at end.
#define MB   256
#define NCB  256
#define BK   32
#define NTH  512
#define NCHN (CODES / NCB)     // 8
#define KT   (SEM / BK)        // 16
#define PL   8192              // f16 per plane (256*32)
#define BUF  32768             // f16 per buffer (4 planes)

__device__ __forceinline__ void gl_lds16(const f16* g, f16* l) {
    __builtin_amdgcn_global_load_lds(
        (const __attribute__((address_space(1))) unsigned int*)(g),
        (__attribute__((address_space(3))) unsigned int*)(l),
        16, 0, 0);
}

__global__ __launch_bounds__(NTH, 2) void argmin_mfma(
        const f16* __restrict__ XhT, const f16* __restrict__ XlT,
        const f16* __restrict__ EhT, const f16* __restrict__ ElT,
        const float* __restrict__ bias,
        int* __restrict__ codesW, float* __restrict__ codes_out) {
    __shared__ __align__(16) f16 smem[2 * BUF];   // 128 KB

    int tid = threadIdx.x;
    int w   = tid >> 6;        // wave 0..7
    int l   = tid & 63;
    int q   = l >> 4;          // quad
    int r16 = l & 15;
    int wm  = w >> 1;          // 0..3  (m-tile of 64)
    int wn  = w & 1;           // 0..1  (n-half of 128)

    int m0 = blockIdx.x * MB;

    // staging: 4096 x 16B chunks/buffer; 8 per thread; lane-linear LDS dest
    int sr = tid >> 2;         // 0..127
    int sc = (tid & 3) * 8;    // f16 col within 32-row

    float bestS[16];
    int   bestI[16];
#pragma unroll
    for (int i = 0; i < 16; i++) { bestS[i] = -3.4e38f; bestI[i] = 0; }

    f32x4 acc[4][8];
#pragma unroll
    for (int mi = 0; mi < 4; mi++)
#pragma unroll
        for (int ni = 0; ni < 8; ni++)
            acc[mi][ni] = (f32x4){0.f, 0.f, 0.f, 0.f};

#define STAGE(BI, NB, KK) do {                                              \
    f16* sb = smem + (BI) * BUF;                                            \
    _Pragma("unroll")                                                       \
    for (int ii = 0; ii < 8; ii++) {                                        \
        int rr = (ii & 1) * 128 + sr;                                       \
        int ldsOff = (ii >> 1) * PL + rr * 32 + sc;                         \
        const f16* g;                                                       \
        if ((ii >> 1) == 0)      g = XhT + (size_t)(m0 + rr) * SEM + (KK) + sc; \
        else if ((ii >> 1) == 1) g = XlT + (size_t)(m0 + rr) * SEM + (KK) + sc; \
        else if ((ii >> 1) == 2) g = EhT + (size_t)((NB) + rr) * SEM + (KK) + sc; \
        else                     g = ElT + (size_t)((NB) + rr) * SEM + (KK) + sc; \
        gl_lds16(g, sb + ldsOff);                                           \
    }                                                                       \
} while (0)

    // prologue: stage tile 0 into buffer 0
    STAGE(0, 0, 0);
    __syncthreads();

    for (int t = 0; t < NCHN * KT; t++) {
        int cur   = t & 1;
        int nbase = (t >> 4) * NCB;

        // prefetch next tile into the other buffer (issued BEFORE compute)
        if (t + 1 < NCHN * KT) {
            int t1 = t + 1;
            STAGE(cur ^ 1, (t1 >> 4) * NCB, (t1 & 15) * BK);
        }

        // compute from current buffer
        const f16* bp = smem + cur * BUF;
        f16x8 ah[4], al[4];
#pragma unroll
        for (int mi = 0; mi < 4; mi++) {
            int ao = (wm * 64 + mi * 16 + r16) * 32 + q * 8;
            ah[mi] = *(const f16x8*)&bp[ao];
            al[mi] = *(const f16x8*)&bp[ao + PL];
        }
#pragma unroll
        for (int ni = 0; ni < 8; ni++) {
            int bo = 2 * PL + (wn * 128 + ni * 16 + r16) * 32 + q * 8;
            f16x8 bh = *(const f16x8*)&bp[bo];
            f16x8 bl = *(const f16x8*)&bp[bo + PL];
#pragma unroll
            for (int mi = 0; mi < 4; mi++) {
                f32x4 a0 = acc[mi][ni];
                a0 = __builtin_amdgcn_mfma_f32_16x16x32_f16(al[mi], bh, a0, 0, 0, 0);
                a0 = __builtin_amdgcn_mfma_f32_16x16x32_f16(ah[mi], bl, a0, 0, 0, 0);
                a0 = __builtin_amdgcn_mfma_f32_16x16x32_f16(ah[mi], bh, a0, 0, 0, 0);
                acc[mi][ni] = a0;
            }
        }

        // end of an nc-chunk: fold bias, update best, reset acc
        if ((t & 15) == 15) {
#pragma unroll
            for (int ni = 0; ni < 8; ni++) {
                int n = nbase + wn * 128 + ni * 16 + r16;
                float bb = bias[n];
#pragma unroll
                for (int mi = 0; mi < 4; mi++)
#pragma unroll
                    for (int reg = 0; reg < 4; reg++) {
                        float s = acc[mi][ni][reg] - bb;
                        int slot = mi * 4 + reg;
                        if (s > bestS[slot]) { bestS[slot] = s; bestI[slot] = n; }
                        acc[mi][ni][reg] = 0.f;
                    }
            }
        }
        __syncthreads();   // drains prefetch vmcnt + guards buffer swap
    }

    // reduce across the 16 column-lanes (bits 0..3), tie -> smallest idx
#pragma unroll
    for (int mask = 1; mask < 16; mask <<= 1) {
#pragma unroll
        for (int slot = 0; slot < 16; slot++) {
            float os = __shfl_xor(bestS[slot], mask);
            int   oi = __shfl_xor(bestI[slot], mask);
            if (os > bestS[slot] || (os == bestS[slot] && oi < bestI[slot])) {
                bestS[slot] = os; bestI[slot] = oi;
            }
        }
    }

    // ---- cross-wave merge: wave (wm, wn=1) -> wave (wm, wn=0) via LDS ----
    // smem is dead here (all waves past the final loop barrier).
    // Each wave's r16==0 lanes (q=0..3) hold 16 reduced slots.
    {
        float* sMS = (float*)smem;              // [8 waves][4 q][16 slots]
        int*   sMI = (int*)(sMS + 8 * 4 * 16);
        if (r16 == 0) {
            int base = (w * 4 + q) * 16;
#pragma unroll
            for (int slot = 0; slot < 16; slot++) {
                sMS[base + slot] = bestS[slot];
                sMI[base + slot] = bestI[slot];
            }
        }
        __syncthreads();
        if (wn == 0 && r16 == 0) {
            int pbase = ((w + 1) * 4 + q) * 16;
#pragma unroll
            for (int slot = 0; slot < 16; slot++) {
                float os = sMS[pbase + slot];
                int   oi = sMI[pbase + slot];
                if (os > bestS[slot] || (os == bestS[slot] && oi < bestI[slot])) {
                    bestS[slot] = os; bestI[slot] = oi;
                }
            }
#pragma unroll
            for (int mi = 0; mi < 4; mi++)
#pragma unroll
                for (int reg = 0; reg < 4; reg++) {
                    int m = m0 + wm * 64 + mi * 16 + q * 4 + reg;
                    int bi = bestI[mi * 4 + reg];
                    codesW[m] = bi;
                    int bb2 = m >> 12, tt = m & 4095;
                    codes_out[(size_t)bb2 * 33 * T_ + tt] = (float)bi;
                }
        }
    }
#undef STAGE
}

// ============ kernel 6: finalize (sem select/gather + aco path) ============
__global__ void finalize_kernel(const float* __restrict__ x,
                                const float* __restrict__ embT,
                                const int* __restrict__ codes_ws,
                                const float* __restrict__ noise,
                                const float* __restrict__ probs_sem,
                                const float* __restrict__ probs_aco,
                                float* __restrict__ out,
                                float* __restrict__ codes_out) {
    const size_t N0 = (size_t)B_ * SEM * T_;   // 33,554,432
    const size_t N1 = (size_t)B_ * ACO * T_;   // 2,097,152
    size_t idx = (size_t)blockIdx.x * 256 + threadIdx.x;
    if (idx < N0) {
        int t = (int)(idx & 4095);
        int d = (int)((idx >> 12) & 511);
        int b = (int)(idx >> 21);
        float v;
        if (probs_sem[b] < 0.5f) {
            int c = codes_ws[(b << 12) + t];
            v = embT[(size_t)d * CODES + c];
        } else {
            v = x[((size_t)(b * XROWS + d)) * T_ + t];
        }
        out[((size_t)(b * XROWS + d)) * T_ + t] = v;
    } else if (idx < N0 + N1) {
        size_t i2 = idx - N0;
        int t = (int)(i2 & 4095);
        int j = (int)((i2 >> 12) & 31);
        int b = (int)(i2 >> 17);
        float a  = x[((size_t)(b * XROWS + SEM + j)) * T_ + t];
        float zb = tanhf(a) * HALFC;
        float p  = probs_aco[b];
        float zo;
        if (p < 0.5f) {
            zo = rintf(zb);                         // round-half-even, matches jnp.round
        } else if (p < 0.75f) {
            float nz = noise[((size_t)(b * ACO + j)) * T_ + t];
            float ns = ((nz * 2.0f - 1.0f) * (float)(1.0 / 9.0)) * HALFC;
            zo = fminf(fmaxf(zb + ns, -HALFC), HALFC);
        } else {
            zo = zb;
        }
        float code = fminf(fmaxf(rintf(zo + HALFC), 0.f), 8.f);
        out[((size_t)(b * XROWS + SEM + j)) * T_ + t] = zo * 0.25f;
        codes_out[((size_t)(b * 33 + 1 + j)) * T_ + t] = code;
    }
}

extern "C" void kernel_launch(void* const* d_in, const int* in_sizes, int n_in,
                              void* d_out, int out_size, void* d_ws, size_t ws_size,
                              hipStream_t stream) {
    const float* x      = (const float*)d_in[0];
    const float* esum   = (const float*)d_in[1];
    const float* usage  = (const float*)d_in[2];
    const float* noise  = (const float*)d_in[3];
    const float* psem   = (const float*)d_in[4];
    const float* paco   = (const float*)d_in[5];
    float* out = (float*)d_out;

    float* wsf    = (float*)d_ws;
    float* embT   = wsf;
    float* bias   = wsf + 1048576;
    int*   codesW = (int*)(wsf + 1050624);
    f16*   EhT    = (f16*)(wsf + 1116160);
    f16*   ElT    = (f16*)(wsf + 1640448);

    const size_t QOFF = (size_t)B_ * XROWS * T_;   // 35,651,584
    float* codes_out = out + QOFF;

    // X hi/lo scratch inside the output buffer (consumed before finalize writes)
    f16* XhT = (f16*)out;                    // 64 MB
    f16* XlT = (f16*)(out + 16777216);       // 64 MB, ends at 33,554,432 < QOFF

    xsplit_kernel<<<dim3((B_ * T_) / 256, SEM / 32), 256, 0, stream>>>(x, XhT, XlT);
    bias_kernel<<<CODES, 64, 0, stream>>>(esum, usage, bias);
    embT_kernel<<<dim3(CODES / 32, SEM / 32), 256, 0, stream>>>(esum, usage, embT);
    esplit_kernel<<<CODES, 256, 0, stream>>>(esum, usage, EhT, ElT);
    argmin_mfma<<<(B_ * T_) / MB, NTH, 0, stream>>>(XhT, XlT, EhT, ElT, bias,
                                                    codesW, codes_out);
    const size_t NTOT = (size_t)B_ * SEM * T_ + (size_t)B_ * ACO * T_;
    finalize_kernel<<<(int)(NTOT / 256), 256, 0, stream>>>(x, embT, codesW, noise,
                                                           psem, paco, out, codes_out);
}

// Round 4
// 719.021 us; speedup vs baseline: 1.2281x; 1.0004x over previous
//
#include <hip/hip_runtime.h>
#include <math.h>
#include <stdint.h>

typedef _Float16 f16;
typedef _Float16 f16x8 __attribute__((ext_vector_type(8)));
typedef float f32x4 __attribute__((ext_vector_type(4)));

#define B_    16
#define T_    4096
#define SEM   512
#define ACO   32
#define XROWS 544
#define CODES 2048
#define EPSC  1e-5f
#define HALFC 4.0f
#define ECLAMP 60000.0f

// ---- ws layout (float units) ----
// embT   [0, 1048576)              fp32 [512][2048] for finalize gather
// bias   [1048576, 1050624)        0.5*|e|^2
// codesW [1050624, 1116160)        int[65536]
// EhT    [1116160, 1640448)        f16[2048][512] (high half)
// ElT    [1640448, 2164736)        f16[2048][512] (low half)
//
// X hi/lo planes live in the OUTPUT buffer as scratch (finalize overwrites
// them only after argmin has consumed them):
// XhT = out[0, 16777216)  floats   = f16[65536][512]
// XlT = out[16777216, 33554432)    = f16[65536][512]   (QOFF = 35651584 > end)

// ============ kernel 1: per-code bias = 0.5*|e|^2 ============
__global__ void bias_kernel(const float* __restrict__ esum,
                            const float* __restrict__ usage,
                            float* __restrict__ bias) {
    int c = blockIdx.x;
    float u = fmaxf(usage[c], EPSC);
    float s = 0.f;
    for (int d = threadIdx.x; d < SEM; d += 64) {
        float v = esum[(size_t)c * SEM + d] / u;
        s += v * v;
    }
    for (int off = 32; off; off >>= 1) s += __shfl_down(s, off);
    if (threadIdx.x == 0) bias[c] = 0.5f * s;
}

// ============ kernel 2: embT[d][c] = esum[c][d] / clip(usage[c]) ============
__global__ void embT_kernel(const float* __restrict__ esum,
                            const float* __restrict__ usage,
                            float* __restrict__ embT) {
    __shared__ float tile[32][33];
    int c0 = blockIdx.x * 32;
    int d0 = blockIdx.y * 32;
    int col = threadIdx.x & 31, r = threadIdx.x >> 5;  // 256 threads: r=0..7
    for (int i = r; i < 32; i += 8) {
        float u = fmaxf(usage[c0 + i], EPSC);
        tile[col][i] = esum[(size_t)(c0 + i) * SEM + d0 + col] / u;
    }
    __syncthreads();
    for (int i = r; i < 32; i += 8)
        embT[(size_t)(d0 + i) * CODES + c0 + col] = tile[i][col];
}

// ============ kernel 3: f16 hi/lo split planes of emb, [c][d] layout ============
__global__ void esplit_kernel(const float* __restrict__ esum,
                              const float* __restrict__ usage,
                              f16* __restrict__ EhT, f16* __restrict__ ElT) {
    int c = blockIdx.x;
    float u = fmaxf(usage[c], EPSC);
    for (int d = threadIdx.x; d < SEM; d += 256) {
        float e = esum[(size_t)c * SEM + d] / u;
        e = fminf(fmaxf(e, -ECLAMP), ECLAMP);
        f16 h = (f16)e;
        EhT[(size_t)c * SEM + d] = h;
        ElT[(size_t)c * SEM + d] = (f16)(e - (float)h);
    }
}

// ============ kernel 3b: transpose+split x -> XhT/XlT [m][k] f16 ============
__global__ void xsplit_kernel(const float* __restrict__ x,
                              f16* __restrict__ XhT, f16* __restrict__ XlT) {
    int m0 = blockIdx.x * 256;
    int d0 = blockIdx.y * 32;
    int b  = m0 >> 12;
    int t  = (m0 & 4095) + (int)threadIdx.x;
    const float* xp = x + ((size_t)b * XROWS + d0) * T_ + t;
    int m = m0 + (int)threadIdx.x;

    f16x8 hv[4], lv[4];
#pragma unroll
    for (int j = 0; j < 4; j++) {
#pragma unroll
        for (int e = 0; e < 8; e++) {
            float v = xp[(size_t)(j * 8 + e) * T_];
            f16 h = (f16)v;
            hv[j][e] = h;
            lv[j][e] = (f16)(v - (float)h);
        }
    }
    f16* oh = XhT + (size_t)m * SEM + d0;
    f16* ol = XlT + (size_t)m * SEM + d0;
#pragma unroll
    for (int j = 0; j < 4; j++) {
        *(f16x8*)(oh + j * 8) = hv[j];
        *(f16x8*)(ol + j * 8) = lv[j];
    }
}

// ============ kernel 4: MFMA GEMM + fused argmin ============
// 512 threads (8 waves = 4M x 2N), MB=256 m-rows, full N=2048 per block via
// 8 nc-chunks of 256 codes; double-buffered LDS (2 x 64 KB) with
// prefetch-before-compute: one barrier per k-tile.
// T2 bank-conflict fix: LDS rows are 64B (32 f16); reads at row*64 + q*16
// were 8-way conflicted. Swizzle: chunk' = chunk ^ ((row>>1)&3), applied on
// the GLOBAL source in STAGE (LDS dest must stay lane-linear for
// global_load_lds) and on the per-lane read offset. Pure permutation ->
// bit-identical math.
#define MB   256
#define NCB  256
#define BK   32
#define NTH  512
#define NCHN (CODES / NCB)     // 8
#define KT   (SEM / BK)        // 16
#define PL   8192              // f16 per plane (256*32)
#define BUF  32768             // f16 per buffer (4 planes)

__device__ __forceinline__ void gl_lds16(const f16* g, f16* l) {
    __builtin_amdgcn_global_load_lds(
        (const __attribute__((address_space(1))) unsigned int*)(g),
        (__attribute__((address_space(3))) unsigned int*)(l),
        16, 0, 0);
}

__global__ __launch_bounds__(NTH, 2) void argmin_mfma(
        const f16* __restrict__ XhT, const f16* __restrict__ XlT,
        const f16* __restrict__ EhT, const f16* __restrict__ ElT,
        const float* __restrict__ bias,
        int* __restrict__ codesW, float* __restrict__ codes_out) {
    __shared__ __align__(16) f16 smem[2 * BUF];   // 128 KB

    int tid = threadIdx.x;
    int w   = tid >> 6;        // wave 0..7
    int l   = tid & 63;
    int q   = l >> 4;          // quad
    int r16 = l & 15;
    int wm  = w >> 1;          // 0..3  (m-tile of 64)
    int wn  = w & 1;           // 0..1  (n-half of 128)

    int m0 = blockIdx.x * MB;

    // staging: 4096 x 16B chunks/buffer; 8 per thread; lane-linear LDS dest
    int sr = tid >> 2;         // 0..127  (LDS row within 128-row half)
    int sc = (tid & 3) * 8;    // LDS f16 col (lane-linear dest, unswizzled)
    // swizzled GLOBAL source column: chunk c=tid&3, s(row)=(row>>1)&3=(tid>>3)&3
    int scz = (((tid & 3) ^ ((tid >> 3) & 3))) * 8;

    // swizzled read chunk: q' = q ^ ((row>>1)&3) = q ^ ((r16>>1)&3)
    int qs8 = (q ^ ((r16 >> 1) & 3)) * 8;

    float bestS[16];
    int   bestI[16];
#pragma unroll
    for (int i = 0; i < 16; i++) { bestS[i] = -3.4e38f; bestI[i] = 0; }

    f32x4 acc[4][8];
#pragma unroll
    for (int mi = 0; mi < 4; mi++)
#pragma unroll
        for (int ni = 0; ni < 8; ni++)
            acc[mi][ni] = (f32x4){0.f, 0.f, 0.f, 0.f};

#define STAGE(BI, NB, KK) do {                                              \
    f16* sb = smem + (BI) * BUF;                                            \
    _Pragma("unroll")                                                       \
    for (int ii = 0; ii < 8; ii++) {                                        \
        int rr = (ii & 1) * 128 + sr;                                       \
        int ldsOff = (ii >> 1) * PL + rr * 32 + sc;                         \
        const f16* g;                                                       \
        if ((ii >> 1) == 0)      g = XhT + (size_t)(m0 + rr) * SEM + (KK) + scz; \
        else if ((ii >> 1) == 1) g = XlT + (size_t)(m0 + rr) * SEM + (KK) + scz; \
        else if ((ii >> 1) == 2) g = EhT + (size_t)((NB) + rr) * SEM + (KK) + scz; \
        else                     g = ElT + (size_t)((NB) + rr) * SEM + (KK) + scz; \
        gl_lds16(g, sb + ldsOff);                                           \
    }                                                                       \
} while (0)

    // prologue: stage tile 0 into buffer 0
    STAGE(0, 0, 0);
    __syncthreads();

    for (int t = 0; t < NCHN * KT; t++) {
        int cur   = t & 1;
        int nbase = (t >> 4) * NCB;

        // prefetch next tile into the other buffer (issued BEFORE compute)
        if (t + 1 < NCHN * KT) {
            int t1 = t + 1;
            STAGE(cur ^ 1, (t1 >> 4) * NCB, (t1 & 15) * BK);
        }

        // compute from current buffer (reads use swizzled chunk qs8)
        const f16* bp = smem + cur * BUF;
        f16x8 ah[4], al[4];
#pragma unroll
        for (int mi = 0; mi < 4; mi++) {
            int ao = (wm * 64 + mi * 16 + r16) * 32 + qs8;
            ah[mi] = *(const f16x8*)&bp[ao];
            al[mi] = *(const f16x8*)&bp[ao + PL];
        }
#pragma unroll
        for (int ni = 0; ni < 8; ni++) {
            int bo = 2 * PL + (wn * 128 + ni * 16 + r16) * 32 + qs8;
            f16x8 bh = *(const f16x8*)&bp[bo];
            f16x8 bl = *(const f16x8*)&bp[bo + PL];
#pragma unroll
            for (int mi = 0; mi < 4; mi++) {
                f32x4 a0 = acc[mi][ni];
                a0 = __builtin_amdgcn_mfma_f32_16x16x32_f16(al[mi], bh, a0, 0, 0, 0);
                a0 = __builtin_amdgcn_mfma_f32_16x16x32_f16(ah[mi], bl, a0, 0, 0, 0);
                a0 = __builtin_amdgcn_mfma_f32_16x16x32_f16(ah[mi], bh, a0, 0, 0, 0);
                acc[mi][ni] = a0;
            }
        }

        // end of an nc-chunk: fold bias, update best, reset acc
        if ((t & 15) == 15) {
#pragma unroll
            for (int ni = 0; ni < 8; ni++) {
                int n = nbase + wn * 128 + ni * 16 + r16;
                float bb = bias[n];
#pragma unroll
                for (int mi = 0; mi < 4; mi++)
#pragma unroll
                    for (int reg = 0; reg < 4; reg++) {
                        float s = acc[mi][ni][reg] - bb;
                        int slot = mi * 4 + reg;
                        if (s > bestS[slot]) { bestS[slot] = s; bestI[slot] = n; }
                        acc[mi][ni][reg] = 0.f;
                    }
            }
        }
        __syncthreads();   // drains prefetch vmcnt + guards buffer swap
    }

    // reduce across the 16 column-lanes (bits 0..3), tie -> smallest idx
#pragma unroll
    for (int mask = 1; mask < 16; mask <<= 1) {
#pragma unroll
        for (int slot = 0; slot < 16; slot++) {
            float os = __shfl_xor(bestS[slot], mask);
            int   oi = __shfl_xor(bestI[slot], mask);
            if (os > bestS[slot] || (os == bestS[slot] && oi < bestI[slot])) {
                bestS[slot] = os; bestI[slot] = oi;
            }
        }
    }

    // ---- cross-wave merge: wave (wm, wn=1) -> wave (wm, wn=0) via LDS ----
    // smem is dead here (all waves past the final loop barrier).
    // Each wave's r16==0 lanes (q=0..3) hold 16 reduced slots.
    {
        float* sMS = (float*)smem;              // [8 waves][4 q][16 slots]
        int*   sMI = (int*)(sMS + 8 * 4 * 16);
        if (r16 == 0) {
            int base = (w * 4 + q) * 16;
#pragma unroll
            for (int slot = 0; slot < 16; slot++) {
                sMS[base + slot] = bestS[slot];
                sMI[base + slot] = bestI[slot];
            }
        }
        __syncthreads();
        if (wn == 0 && r16 == 0) {
            int pbase = ((w + 1) * 4 + q) * 16;
#pragma unroll
            for (int slot = 0; slot < 16; slot++) {
                float os = sMS[pbase + slot];
                int   oi = sMI[pbase + slot];
                if (os > bestS[slot] || (os == bestS[slot] && oi < bestI[slot])) {
                    bestS[slot] = os; bestI[slot] = oi;
                }
            }
#pragma unroll
            for (int mi = 0; mi < 4; mi++)
#pragma unroll
                for (int reg = 0; reg < 4; reg++) {
                    int m = m0 + wm * 64 + mi * 16 + q * 4 + reg;
                    int bi = bestI[mi * 4 + reg];
                    codesW[m] = bi;
                    int bb2 = m >> 12, tt = m & 4095;
                    codes_out[(size_t)bb2 * 33 * T_ + tt] = (float)bi;
                }
        }
    }
#undef STAGE
}

// ============ kernel 6: finalize (sem select/gather + aco path) ============
__global__ void finalize_kernel(const float* __restrict__ x,
                                const float* __restrict__ embT,
                                const int* __restrict__ codes_ws,
                                const float* __restrict__ noise,
                                const float* __restrict__ probs_sem,
                                const float* __restrict__ probs_aco,
                                float* __restrict__ out,
                                float* __restrict__ codes_out) {
    const size_t N0 = (size_t)B_ * SEM * T_;   // 33,554,432
    const size_t N1 = (size_t)B_ * ACO * T_;   // 2,097,152
    size_t idx = (size_t)blockIdx.x * 256 + threadIdx.x;
    if (idx < N0) {
        int t = (int)(idx & 4095);
        int d = (int)((idx >> 12) & 511);
        int b = (int)(idx >> 21);
        float v;
        if (probs_sem[b] < 0.5f) {
            int c = codes_ws[(b << 12) + t];
            v = embT[(size_t)d * CODES + c];
        } else {
            v = x[((size_t)(b * XROWS + d)) * T_ + t];
        }
        out[((size_t)(b * XROWS + d)) * T_ + t] = v;
    } else if (idx < N0 + N1) {
        size_t i2 = idx - N0;
        int t = (int)(i2 & 4095);
        int j = (int)((i2 >> 12) & 31);
        int b = (int)(i2 >> 17);
        float a  = x[((size_t)(b * XROWS + SEM + j)) * T_ + t];
        float zb = tanhf(a) * HALFC;
        float p  = probs_aco[b];
        float zo;
        if (p < 0.5f) {
            zo = rintf(zb);                         // round-half-even, matches jnp.round
        } else if (p < 0.75f) {
            float nz = noise[((size_t)(b * ACO + j)) * T_ + t];
            float ns = ((nz * 2.0f - 1.0f) * (float)(1.0 / 9.0)) * HALFC;
            zo = fminf(fmaxf(zb + ns, -HALFC), HALFC);
        } else {
            zo = zb;
        }
        float code = fminf(fmaxf(rintf(zo + HALFC), 0.f), 8.f);
        out[((size_t)(b * XROWS + SEM + j)) * T_ + t] = zo * 0.25f;
        codes_out[((size_t)(b * 33 + 1 + j)) * T_ + t] = code;
    }
}

extern "C" void kernel_launch(void* const* d_in, const int* in_sizes, int n_in,
                              void* d_out, int out_size, void* d_ws, size_t ws_size,
                              hipStream_t stream) {
    const float* x      = (const float*)d_in[0];
    const float* esum   = (const float*)d_in[1];
    const float* usage  = (const float*)d_in[2];
    const float* noise  = (const float*)d_in[3];
    const float* psem   = (const float*)d_in[4];
    const float* paco   = (const float*)d_in[5];
    float* out = (float*)d_out;

    float* wsf    = (float*)d_ws;
    float* embT   = wsf;
    float* bias   = wsf + 1048576;
    int*   codesW = (int*)(wsf + 1050624);
    f16*   EhT    = (f16*)(wsf + 1116160);
    f16*   ElT    = (f16*)(wsf + 1640448);

    const size_t QOFF = (size_t)B_ * XROWS * T_;   // 35,651,584
    float* codes_out = out + QOFF;

    // X hi/lo scratch inside the output buffer (consumed before finalize writes)
    f16* XhT = (f16*)out;                    // 64 MB
    f16* XlT = (f16*)(out + 16777216);       // 64 MB, ends at 33,554,432 < QOFF

    xsplit_kernel<<<dim3((B_ * T_) / 256, SEM / 32), 256, 0, stream>>>(x, XhT, XlT);
    bias_kernel<<<CODES, 64, 0, stream>>>(esum, usage, bias);
    embT_kernel<<<dim3(CODES / 32, SEM / 32), 256, 0, stream>>>(esum, usage, embT);
    esplit_kernel<<<CODES, 256, 0, stream>>>(esum, usage, EhT, ElT);
    argmin_mfma<<<(B_ * T_) / MB, NTH, 0, stream>>>(XhT, XlT, EhT, ElT, bias,
                                                    codesW, codes_out);
    const size_t NTOT = (size_t)B_ * SEM * T_ + (size_t)B_ * ACO * T_;
    finalize_kernel<<<(int)(NTOT / 256), 256, 0, stream>>>(x, embT, codesW, noise,
                                                           psem, paco, out, codes_out);
}